// Round 1
// baseline (308.943 us; speedup 1.0000x reference)
//
#include <hip/hip_runtime.h>
#include <hip/hip_bf16.h>

#define L 4096
#define NT 256
#define PPT (L / NT)          // 16 elements per thread
#define PAIRS (L / 2)         // 2048
#define PPTP (PAIRS / NT)     // 8 pairs per thread per stage

__global__ void zero_out_kernel(float* out) { out[0] = 0.0f; }

__global__ __launch_bounds__(NT) void listmle_kernel(
    const float* __restrict__ preds, const float* __restrict__ labels,
    float* __restrict__ out, float invB) {
  __shared__ unsigned long long keys[L];   // 32 KB
  __shared__ float pl[L];                  // 16 KB: preds copy for gather
  __shared__ float red[NT];                // scan scratch
  __shared__ float wmax[4], wsum[4];
  __shared__ float sM, sSum;

  const int row = blockIdx.x;
  const int tid = threadIdx.x;
  const float* __restrict__ prow = preds + (size_t)row * L;
  const float* __restrict__ lrow = labels + (size_t)row * L;

  // ---- load, build sort keys, reduce max & sum of preds ----
  float lmax = -INFINITY;
  float lsum = 0.0f;
  for (int i = tid; i < L; i += NT) {
    float p = prow[i];
    pl[i] = p;
    lmax = fmaxf(lmax, p);
    lsum += p;
    unsigned u = __float_as_uint(lrow[i]);
    unsigned s = (u & 0x80000000u) ? ~u : (u | 0x80000000u);  // ascending-float sortable
    s = ~s;                                                   // descending label
    keys[i] = ((unsigned long long)s << 12) | (unsigned)i;    // tie-break: ascending index
  }
  // wave (64-lane) reduction
  for (int off = 32; off > 0; off >>= 1) {
    lmax = fmaxf(lmax, __shfl_down(lmax, off));
    lsum += __shfl_down(lsum, off);
  }
  const int wave = tid >> 6, lane = tid & 63;
  if (lane == 0) { wmax[wave] = lmax; wsum[wave] = lsum; }
  __syncthreads();   // also publishes keys[] and pl[]
  if (tid == 0) {
    float m = wmax[0], s = wsum[0];
    for (int w = 1; w < 4; ++w) { m = fmaxf(m, wmax[w]); s += wsum[w]; }
    sM = m; sSum = s;
  }
  __syncthreads();

  // ---- bitonic sort (ascending keys == descending labels, stable) ----
  for (int k = 2; k <= L; k <<= 1) {
    for (int j = k >> 1; j > 0; j >>= 1) {
#pragma unroll
      for (int q = 0; q < PPTP; ++q) {
        int p = tid + q * NT;
        int i = ((p & ~(j - 1)) << 1) | (p & (j - 1));
        int partner = i | j;
        bool up = ((i & k) == 0);
        unsigned long long a = keys[i];
        unsigned long long b = keys[partner];
        if ((a > b) == up) { keys[i] = b; keys[partner] = a; }
      }
      __syncthreads();
    }
  }

  // ---- gather sorted preds, exp(x - M) into registers ----
  const float M = sM;
  const int base = tid * PPT;
  float ev[PPT];
#pragma unroll
  for (int i = 0; i < PPT; ++i) {
    unsigned long long k = keys[base + i];
    int idx = (int)(k & 0xFFFu);
    ev[i] = __expf(pl[idx] - M);
  }

  // ---- reverse (suffix) inclusive scan: thread-local part ----
  float suf[PPT];
  float run = 0.0f;
#pragma unroll
  for (int i = PPT - 1; i >= 0; --i) { run += ev[i]; suf[i] = run; }

  // ---- 256-wide suffix scan of chunk totals (Hillis-Steele) ----
  red[tid] = run;
  const float T = run;
  __syncthreads();
  for (int d = 1; d < NT; d <<= 1) {
    float v = (tid + d < NT) ? red[tid + d] : 0.0f;
    __syncthreads();
    red[tid] += v;
    __syncthreads();
  }
  const float O = red[tid] - T;  // sum over later chunks (larger r)

  // ---- sum of log(c_r) ----
  float slog = 0.0f;
#pragma unroll
  for (int i = 0; i < PPT; ++i) slog += __logf(suf[i] + O);

  for (int off = 32; off > 0; off >>= 1) slog += __shfl_down(slog, off);
  if (lane == 0) wsum[wave] = slog;
  __syncthreads();
  if (tid == 0) {
    float tot = wsum[0] + wsum[1] + wsum[2] + wsum[3];
    float rowval = (float)L * M + tot - sSum;
    atomicAdd(out, rowval * invB);
  }
}

extern "C" void kernel_launch(void* const* d_in, const int* in_sizes, int n_in,
                              void* d_out, int out_size, void* d_ws, size_t ws_size,
                              hipStream_t stream) {
  const float* preds = (const float*)d_in[0];
  const float* labels = (const float*)d_in[1];
  float* out = (float*)d_out;
  const int B = in_sizes[0] / L;

  zero_out_kernel<<<1, 1, 0, stream>>>(out);
  listmle_kernel<<<B, NT, 0, stream>>>(preds, labels, out, 1.0f / (float)B);
}

// Round 2
// 150.695 us; speedup vs baseline: 2.0501x; 2.0501x over previous
//
#include <hip/hip_runtime.h>
#include <hip/hip_bf16.h>

#define L 4096
#define NT 256
#define PPT 16          // elements per thread
#define NPASS 5         // 4-bit digits over 20-bit truncated label key

// Padded LDS index: stride-17 per 16 elements -> conflict-free chunk access
__device__ __forceinline__ int PIDX(int p) { return p + (p >> 4); }
#define PADSZ (L + L / 16)   // 4352

__global__ void zero_out_kernel(float* out) { out[0] = 0.0f; }

__global__ __launch_bounds__(NT) void listmle_kernel(
    const float* __restrict__ preds, const float* __restrict__ labels,
    float* __restrict__ out, float invB) {
  __shared__ unsigned int bufA[PADSZ];   // 17 KB
  __shared__ unsigned int bufB[PADSZ];   // 17 KB
  __shared__ float pl[L];                // 16 KB preds for final gather
  __shared__ unsigned int hist[PADSZ];   // 17 KB (4096 entries, padded)
  __shared__ float wredf[4];
  __shared__ float wmax[4];
  __shared__ unsigned int wredu[4];
  __shared__ float sM, sSum;

  const int row = blockIdx.x;
  const int tid = threadIdx.x;
  const int lane = tid & 63;
  const int wave = tid >> 6;
  const float* __restrict__ prow = preds + (size_t)row * L;
  const float* __restrict__ lrow = labels + (size_t)row * L;

  // ---- load (coalesced strided), build sort items, reduce max & sum ----
  float lmax = -INFINITY, lsum = 0.0f;
#pragma unroll
  for (int q = 0; q < PPT; ++q) {
    int i = tid + q * NT;
    float p = prow[i];
    pl[i] = p;
    lmax = fmaxf(lmax, p);
    lsum += p;
    unsigned u = __float_as_uint(lrow[i]);
    unsigned s = (u & 0x80000000u) ? ~u : (u | 0x80000000u);  // ascending sortable
    unsigned d = ~s;                                          // descending label
    bufA[PIDX(i)] = (d & 0xFFFFF000u) | (unsigned)i;          // key20 | idx12
  }
  for (int off = 32; off; off >>= 1) {
    lmax = fmaxf(lmax, __shfl_down(lmax, off));
    lsum += __shfl_down(lsum, off);
  }
  if (lane == 0) { wmax[wave] = lmax; wredf[wave] = lsum; }
  __syncthreads();
  if (tid == 0) {
    float m = wmax[0], s = wredf[0];
    for (int w = 1; w < 4; ++w) { m = fmaxf(m, wmax[w]); s += wredf[w]; }
    sM = m; sSum = s;
  }
  __syncthreads();

  // ---- LSD radix sort: 5 passes of 4 bits over item bits [12..31] ----
  unsigned int* src = bufA;
  unsigned int* dst = bufB;
  for (int pass = 0; pass < NPASS; ++pass) {
    const int sh = 12 + 4 * pass;
    unsigned kv[PPT];
    unsigned long long c0 = 0, c1 = 0;        // 16 x 8-bit digit counters
    unsigned long long dpack = 0, clpack = 0; // 16 x 4-bit digit / local-rank
#pragma unroll
    for (int e = 0; e < PPT; ++e) {
      unsigned v = src[PIDX(tid * PPT + e)];
      kv[e] = v;
      int d = (v >> sh) & 15;
      int s8 = (d & 7) * 8;
      unsigned long long cur = (d < 8) ? c0 : c1;
      unsigned cl = (unsigned)((cur >> s8) & 0xFFu);
      cur += (1ull << s8);
      if (d < 8) c0 = cur; else c1 = cur;
      dpack  |= (unsigned long long)(unsigned)d << (4 * e);
      clpack |= (unsigned long long)cl          << (4 * e);
    }
    // hist[d][t] = count of digit d in thread t's chunk (flat order d*NT+t)
#pragma unroll
    for (int d = 0; d < 16; ++d) {
      unsigned cnt = (unsigned)((((d < 8) ? c0 : c1) >> ((d & 7) * 8)) & 0xFFu);
      hist[PIDX(d * NT + tid)] = cnt;
    }
    __syncthreads();
    // exclusive scan of the 4096 hist entries in flat order
    unsigned h[PPT], tot = 0;
#pragma unroll
    for (int e = 0; e < PPT; ++e) {
      unsigned v = hist[PIDX(tid * PPT + e)];
      h[e] = tot;                 // local exclusive prefix
      tot += v;
    }
    unsigned inc = tot;           // wave-inclusive scan of chunk totals
    for (int off = 1; off < 64; off <<= 1) {
      unsigned v = __shfl_up(inc, off);
      if (lane >= off) inc += v;
    }
    if (lane == 63) wredu[wave] = inc;
    __syncthreads();
    unsigned woff = 0;
    for (int w = 0; w < 4; ++w) if (w < wave) woff += wredu[w];
    unsigned off0 = woff + inc - tot;   // global exclusive prefix of my chunk
#pragma unroll
    for (int e = 0; e < PPT; ++e) hist[PIDX(tid * PPT + e)] = off0 + h[e];
    __syncthreads();
    // scatter (stable)
#pragma unroll
    for (int e = 0; e < PPT; ++e) {
      int d = (int)((dpack >> (4 * e)) & 15);
      unsigned cl = (unsigned)((clpack >> (4 * e)) & 15);
      unsigned base = hist[PIDX(d * NT + tid)];
      dst[PIDX((int)(base + cl))] = kv[e];
    }
    __syncthreads();
    unsigned int* tmp = src; src = dst; dst = tmp;
  }
  // after NPASS swaps, `src` points at the sorted buffer

  // ---- gather sorted preds, exp(x - M) ----
  const float M = sM;
  float ev[PPT];
#pragma unroll
  for (int e = 0; e < PPT; ++e) {
    unsigned v = src[PIDX(tid * PPT + e)];
    int idx = (int)(v & 0xFFFu);
    ev[e] = __expf(pl[idx] - M);
  }

  // ---- suffix (reverse inclusive) scan ----
  float suf[PPT];
  float run = 0.0f;
#pragma unroll
  for (int e = PPT - 1; e >= 0; --e) { run += ev[e]; suf[e] = run; }
  float s = run;                       // wave suffix-inclusive scan
  for (int off = 1; off < 64; off <<= 1) {
    float v = __shfl_down(s, off);
    if (lane + off < 64) s += v;
  }
  if (lane == 0) wredf[wave] = s;      // wave total
  __syncthreads();
  float O = s - run;                   // later chunks within wave
  for (int w = wave + 1; w < 4; ++w) O += wredf[w];

  float slog = 0.0f;
#pragma unroll
  for (int e = 0; e < PPT; ++e) slog += __logf(suf[e] + O);

  for (int off = 32; off; off >>= 1) slog += __shfl_down(slog, off);
  if (lane == 0) wmax[wave] = slog;    // reuse as scratch
  __syncthreads();
  if (tid == 0) {
    float tot = wmax[0] + wmax[1] + wmax[2] + wmax[3];
    float rowval = (float)L * M + tot - sSum;
    atomicAdd(out, rowval * invB);
  }
}

extern "C" void kernel_launch(void* const* d_in, const int* in_sizes, int n_in,
                              void* d_out, int out_size, void* d_ws, size_t ws_size,
                              hipStream_t stream) {
  const float* preds = (const float*)d_in[0];
  const float* labels = (const float*)d_in[1];
  float* out = (float*)d_out;
  const int B = in_sizes[0] / L;

  zero_out_kernel<<<1, 1, 0, stream>>>(out);
  listmle_kernel<<<B, NT, 0, stream>>>(preds, labels, out, 1.0f / (float)B);
}

// Round 3
// 148.719 us; speedup vs baseline: 2.0774x; 1.0133x over previous
//
#include <hip/hip_runtime.h>
#include <hip/hip_bf16.h>

#define L 4096
#define NT 256
#define PPT 16          // elements per thread
#define NPASS 5         // 4-bit digits over 20-bit truncated label key

// Padded LDS index: +1 word per 16 -> conflict-free chunk access
__device__ __forceinline__ int PIDX(int p) { return p + (p >> 4); }
#define PADSZ (L + L / 16)   // 4352

__global__ void zero_out_kernel(float* out) { out[0] = 0.0f; }

__global__ __launch_bounds__(NT) void listmle_kernel(
    const float* __restrict__ preds, const float* __restrict__ labels,
    float* __restrict__ out, float invB) {
  __shared__ unsigned int bufA[PADSZ];      // 17 KB
  __shared__ unsigned int bufB[PADSZ];      // 17 KB
  __shared__ unsigned short hist[PADSZ];    // 8.5 KB
  __shared__ float wredf[4];
  __shared__ float wmax[4];
  __shared__ unsigned int wredu[4];
  __shared__ float sM, sSum;

  const int row = blockIdx.x;
  const int tid = threadIdx.x;
  const int lane = tid & 63;
  const int wave = tid >> 6;
  const float* __restrict__ prow = preds + (size_t)row * L;
  const float* __restrict__ lrow = labels + (size_t)row * L;

  // ---- chunk-order vector loads; build keys in registers ----
  unsigned kv[PPT];
  float lmax = -INFINITY, lsum = 0.0f;
  {
    const float4* p4 = reinterpret_cast<const float4*>(prow) + tid * 4;
    const float4* l4 = reinterpret_cast<const float4*>(lrow) + tid * 4;
#pragma unroll
    for (int q = 0; q < 4; ++q) {
      float4 p = p4[q];
      float4 lb = l4[q];
      float pe[4] = {p.x, p.y, p.z, p.w};
      float le[4] = {lb.x, lb.y, lb.z, lb.w};
#pragma unroll
      for (int r = 0; r < 4; ++r) {
        lmax = fmaxf(lmax, pe[r]);
        lsum += pe[r];
        unsigned u = __float_as_uint(le[r]);
        unsigned s = (u & 0x80000000u) ? ~u : (u | 0x80000000u);  // ascending sortable
        unsigned d = ~s;                                          // descending label
        kv[q * 4 + r] = (d & 0xFFFFF000u) | (unsigned)(tid * PPT + q * 4 + r);
      }
    }
  }
  for (int off = 32; off; off >>= 1) {
    lmax = fmaxf(lmax, __shfl_down(lmax, off));
    lsum += __shfl_down(lsum, off);
  }
  if (lane == 0) { wmax[wave] = lmax; wredf[wave] = lsum; }

  // ---- LSD radix: 5 passes of 4 bits over bits [12..31] ----
  // pass 0 consumes kv registers; ping-pong A->B->A->B->A
  unsigned int* src = bufB;   // unused for pass 0
  unsigned int* dst = bufA;
  for (int pass = 0; pass < NPASS; ++pass) {
    const int sh = 12 + 4 * pass;
    if (pass > 0) {
#pragma unroll
      for (int e = 0; e < PPT; ++e) kv[e] = src[PIDX(tid * PPT + e)];
    }
    // per-thread digit counts + stable local ranks
    unsigned long long c0 = 0, c1 = 0, clpack = 0;
#pragma unroll
    for (int e = 0; e < PPT; ++e) {
      int d = (kv[e] >> sh) & 15;
      int s8 = (d & 7) * 8;
      unsigned long long cur = (d < 8) ? c0 : c1;
      unsigned cl = (unsigned)((cur >> s8) & 0xFFu);
      cur += (1ull << s8);
      if (d < 8) c0 = cur; else c1 = cur;
      clpack |= (unsigned long long)cl << (4 * e);
    }
#pragma unroll
    for (int d = 0; d < 16; ++d) {
      unsigned cnt = (unsigned)((((d < 8) ? c0 : c1) >> ((d & 7) * 8)) & 0xFFu);
      hist[PIDX(d * NT + tid)] = (unsigned short)cnt;
    }
    __syncthreads();                       // barrier 1: hist published
    if (pass == 0 && tid == 0) {
      float m = wmax[0], s2 = wredf[0];
      for (int w = 1; w < 4; ++w) { m = fmaxf(m, wmax[w]); s2 += wredf[w]; }
      sM = m; sSum = s2;
    }
    // exclusive scan of 4096 hist entries (flat order)
    unsigned h[PPT], tot = 0;
#pragma unroll
    for (int e = 0; e < PPT; ++e) {
      unsigned v = hist[PIDX(tid * PPT + e)];
      h[e] = tot;
      tot += v;
    }
    unsigned inc = tot;
    for (int off = 1; off < 64; off <<= 1) {
      unsigned v = __shfl_up(inc, off);
      if (lane >= off) inc += v;
    }
    if (lane == 63) wredu[wave] = inc;
    __syncthreads();                       // barrier 2: wave totals
    unsigned woff = 0;
    for (int w = 0; w < 4; ++w) if (w < wave) woff += wredu[w];
    unsigned off0 = woff + inc - tot;
#pragma unroll
    for (int e = 0; e < PPT; ++e)
      hist[PIDX(tid * PPT + e)] = (unsigned short)(off0 + h[e]);
    __syncthreads();                       // barrier 3: offsets published
    // stable scatter
    if (pass == NPASS - 1) {
      const float M = sM;
#pragma unroll
      for (int e = 0; e < PPT; ++e) {
        int d = (kv[e] >> sh) & 15;
        unsigned cl = (unsigned)((clpack >> (4 * e)) & 15);
        unsigned base = hist[PIDX(d * NT + tid)];
        int idx = (int)(kv[e] & 0xFFFu);
        float evv = __expf(prow[idx] - M);          // L1-resident row
        dst[PIDX((int)(base + cl))] = __float_as_uint(evv);
      }
    } else {
#pragma unroll
      for (int e = 0; e < PPT; ++e) {
        int d = (kv[e] >> sh) & 15;
        unsigned cl = (unsigned)((clpack >> (4 * e)) & 15);
        unsigned base = hist[PIDX(d * NT + tid)];
        dst[PIDX((int)(base + cl))] = kv[e];
      }
    }
    __syncthreads();                       // barrier 4: scatter done
    src = dst;
    dst = (dst == bufA) ? bufB : bufA;
  }
  // sorted exp-values are in bufA (pass 4 dst)

  // ---- suffix (reverse inclusive) scan of exp values ----
  float suf[PPT];
  float run = 0.0f;
#pragma unroll
  for (int e = PPT - 1; e >= 0; --e) {
    run += __uint_as_float(bufA[PIDX(tid * PPT + e)]);
    suf[e] = run;
  }
  float s = run;                       // wave suffix-inclusive scan
  for (int off = 1; off < 64; off <<= 1) {
    float v = __shfl_down(s, off);
    if (lane + off < 64) s += v;
  }
  if (lane == 0) wredf[wave] = s;      // wave totals
  __syncthreads();
  float O = s - run;                   // later chunks within wave
  for (int w = wave + 1; w < 4; ++w) O += wredf[w];

  float slog = 0.0f;
#pragma unroll
  for (int e = 0; e < PPT; ++e) slog += __logf(suf[e] + O);

  for (int off = 32; off; off >>= 1) slog += __shfl_down(slog, off);
  if (lane == 0) wmax[wave] = slog;    // reuse as scratch
  __syncthreads();
  if (tid == 0) {
    float tot = wmax[0] + wmax[1] + wmax[2] + wmax[3];
    float rowval = (float)L * sM + tot - sSum;
    atomicAdd(out, rowval * invB);
  }
}

extern "C" void kernel_launch(void* const* d_in, const int* in_sizes, int n_in,
                              void* d_out, int out_size, void* d_ws, size_t ws_size,
                              hipStream_t stream) {
  const float* preds = (const float*)d_in[0];
  const float* labels = (const float*)d_in[1];
  float* out = (float*)d_out;
  const int B = in_sizes[0] / L;

  zero_out_kernel<<<1, 1, 0, stream>>>(out);
  listmle_kernel<<<B, NT, 0, stream>>>(preds, labels, out, 1.0f / (float)B);
}

// Round 4
// 142.622 us; speedup vs baseline: 2.1662x; 1.0428x over previous
//
#include <hip/hip_runtime.h>
#include <hip/hip_bf16.h>

#define L 4096
#define NT 256
#define PPT 16          // elements per thread
#define NPASS 3         // 4-bit digits over 12-bit truncated label key (bits 20..31)

// Padded LDS index: +1 word per 16 -> conflict-free chunk access
__device__ __forceinline__ int PIDX(int p) { return p + (p >> 4); }
#define PADSZ (L + L / 16)   // 4352

__global__ void zero_out_kernel(float* out) { out[0] = 0.0f; }

// x += dpp_move(x) with given ctrl/row_mask; masked/out-of-bounds lanes add 0.
template <int CTRL, int RM>
__device__ __forceinline__ unsigned dpp_add(unsigned x) {
  return x + (unsigned)__builtin_amdgcn_update_dpp(0, (int)x, CTRL, RM, 0xF, false);
}

// Wave64 inclusive +scan of 8 independent u32 (each = 2 packed u16 counters).
__device__ __forceinline__ void wave_incl_scan8(unsigned v[8]) {
#pragma unroll
  for (int k = 0; k < 8; ++k) {
    unsigned x = v[k];
    x = dpp_add<0x111, 0xF>(x);   // row_shr:1
    x = dpp_add<0x112, 0xF>(x);   // row_shr:2
    x = dpp_add<0x114, 0xF>(x);   // row_shr:4
    x = dpp_add<0x118, 0xF>(x);   // row_shr:8
    x = dpp_add<0x142, 0xA>(x);   // row_bcast:15 -> rows 1,3
    x = dpp_add<0x143, 0xC>(x);   // row_bcast:31 -> rows 2,3
    v[k] = x;
  }
}

// Extract u16 entry d (0..15) from 8 packed u32s via cndmask tree.
__device__ __forceinline__ unsigned sel16(const unsigned c[8], int d) {
  unsigned a0 = (d & 2) ? c[1] : c[0];
  unsigned a1 = (d & 2) ? c[3] : c[2];
  unsigned a2 = (d & 2) ? c[5] : c[4];
  unsigned a3 = (d & 2) ? c[7] : c[6];
  unsigned b0 = (d & 4) ? a1 : a0;
  unsigned b1 = (d & 4) ? a3 : a2;
  unsigned w  = (d & 8) ? b1 : b0;
  return (w >> ((d & 1) * 16)) & 0xFFFFu;
}

__global__ __launch_bounds__(NT, 4) void listmle_kernel(
    const float* __restrict__ preds, const float* __restrict__ labels,
    float* __restrict__ out, float invB) {
  __shared__ unsigned int bufA[PADSZ];      // 17 KB
  __shared__ unsigned int bufB[PADSZ];      // 17 KB
  __shared__ uint4 wt4[8];                  // 128 B: per-wave packed digit totals
  __shared__ float wredf[4];
  __shared__ float wmax[4];
  __shared__ float sM, sSum;

  const int row = blockIdx.x;
  const int tid = threadIdx.x;
  const int lane = tid & 63;
  const int wave = tid >> 6;
  const float* __restrict__ prow = preds + (size_t)row * L;
  const float* __restrict__ lrow = labels + (size_t)row * L;

  // ---- chunk-order vector loads; build 12-bit keys in registers ----
  unsigned kv[PPT];
  float lmax = -INFINITY, lsum = 0.0f;
  {
    const float4* p4 = reinterpret_cast<const float4*>(prow) + tid * 4;
    const float4* l4 = reinterpret_cast<const float4*>(lrow) + tid * 4;
#pragma unroll
    for (int q = 0; q < 4; ++q) {
      float4 p = p4[q];
      float4 lb = l4[q];
      float pe[4] = {p.x, p.y, p.z, p.w};
      float le[4] = {lb.x, lb.y, lb.z, lb.w};
#pragma unroll
      for (int r = 0; r < 4; ++r) {
        lmax = fmaxf(lmax, pe[r]);
        lsum += pe[r];
        unsigned u = __float_as_uint(le[r]);
        unsigned s = (u & 0x80000000u) ? ~u : (u | 0x80000000u);  // ascending sortable
        kv[q * 4 + r] = (~s & 0xFFF00000u) | (unsigned)(tid * PPT + q * 4 + r);
      }
    }
  }
  for (int off = 32; off; off >>= 1) {
    lmax = fmaxf(lmax, __shfl_down(lmax, off));
    lsum += __shfl_down(lsum, off);
  }
  if (lane == 0) { wmax[wave] = lmax; wredf[wave] = lsum; }

  // ---- LSD radix: 3 passes of 4 bits over bits [20..31] ----
  unsigned int* src = bufB;   // unused for pass 0
  unsigned int* dst = bufA;
#pragma unroll
  for (int pass = 0; pass < NPASS; ++pass) {
    const int sh = 20 + 4 * pass;
    if (pass > 0) {
#pragma unroll
      for (int e = 0; e < PPT; ++e) kv[e] = src[PIDX(tid * PPT + e)];
    }
    // per-thread digit counts (16 x 8-bit in c0,c1) + stable local ranks
    unsigned long long c0 = 0, c1 = 0, clpack = 0;
#pragma unroll
    for (int e = 0; e < PPT; ++e) {
      int d = (kv[e] >> sh) & 15;
      int s8 = (d & 7) * 8;
      unsigned long long cur = (d < 8) ? c0 : c1;
      unsigned cl = (unsigned)((cur >> s8) & 0xFFu);
      cur += (1ull << s8);
      if (d < 8) c0 = cur; else c1 = cur;
      clpack |= (unsigned long long)cl << (4 * e);
    }
    // expand to 16 x u16 packed in 8 u32 (digit 2k low, 2k+1 high)
    unsigned own[8], incl[8];
#pragma unroll
    for (int k = 0; k < 4; ++k) {
      own[k]     = (unsigned)((c0 >> (16 * k)) & 0xFFu) |
                   ((unsigned)((c0 >> (16 * k + 8)) & 0xFFu) << 16);
      own[4 + k] = (unsigned)((c1 >> (16 * k)) & 0xFFu) |
                   ((unsigned)((c1 >> (16 * k + 8)) & 0xFFu) << 16);
    }
#pragma unroll
    for (int k = 0; k < 8; ++k) incl[k] = own[k];
    wave_incl_scan8(incl);                 // pure VALU (DPP), no LDS
    if (lane == 63) {
      wt4[wave * 2]     = make_uint4(incl[0], incl[1], incl[2], incl[3]);
      wt4[wave * 2 + 1] = make_uint4(incl[4], incl[5], incl[6], incl[7]);
    }
    __syncthreads();                       // barrier 1: wave totals published
    if (pass == 0 && tid == 0) {
      float m = wmax[0], s2 = wredf[0];
      for (int w = 1; w < 4; ++w) { m = fmaxf(m, wmax[w]); s2 += wredf[w]; }
      sM = m; sSum = s2;
    }
    // block digit totals + my wave's exclusive prefix (packed u16, no carry: <=4096)
    unsigned cum[8] = {0,0,0,0,0,0,0,0}, tot[8] = {0,0,0,0,0,0,0,0};
#pragma unroll
    for (int w = 0; w < 4; ++w) {
      uint4 a = wt4[w * 2], b = wt4[w * 2 + 1];
      unsigned tw[8] = {a.x, a.y, a.z, a.w, b.x, b.y, b.z, b.w};
#pragma unroll
      for (int k = 0; k < 8; ++k) {
        tot[k] += tw[k];
        if (w < wave) cum[k] += tw[k];     // wave-uniform predicate
      }
    }
    // exclusive scan over 16 digit totals + combine all offset terms
    unsigned comb[8];
    unsigned run = 0;
#pragma unroll
    for (int k = 0; k < 8; ++k) {
      unsigned t0 = tot[k] & 0xFFFFu, t1 = tot[k] >> 16;
      unsigned b0 = run; run += t0;
      unsigned b1 = run; run += t1;
      comb[k] = (b0 | (b1 << 16)) + cum[k] + (incl[k] - own[k]);
    }
    // stable scatter
    if (pass == NPASS - 1) {
      const float M = sM;
#pragma unroll
      for (int e = 0; e < PPT; ++e) {
        int d = (kv[e] >> sh) & 15;
        unsigned base = sel16(comb, d);
        unsigned cl = (unsigned)((clpack >> (4 * e)) & 15);
        int idx = (int)(kv[e] & 0xFFFu);
        float evv = __expf(prow[idx] - M);     // L1-resident row gather
        dst[PIDX((int)(base + cl))] = __float_as_uint(evv);
      }
    } else {
#pragma unroll
      for (int e = 0; e < PPT; ++e) {
        int d = (kv[e] >> sh) & 15;
        unsigned base = sel16(comb, d);
        unsigned cl = (unsigned)((clpack >> (4 * e)) & 15);
        dst[PIDX((int)(base + cl))] = kv[e];
      }
    }
    __syncthreads();                       // barrier 2: scatter done
    src = dst;
    dst = (dst == bufA) ? bufB : bufA;
  }
  // sorted exp-values are in bufA (pass 2 dst: A->B->A)

  // ---- suffix (reverse inclusive) scan of exp values ----
  float suf[PPT];
  float run = 0.0f;
#pragma unroll
  for (int e = PPT - 1; e >= 0; --e) {
    run += __uint_as_float(bufA[PIDX(tid * PPT + e)]);
    suf[e] = run;
  }
  float s = run;                       // wave suffix-inclusive scan
  for (int off = 1; off < 64; off <<= 1) {
    float v = __shfl_down(s, off);
    if (lane + off < 64) s += v;
  }
  if (lane == 0) wredf[wave] = s;      // wave totals
  __syncthreads();
  float O = s - run;                   // later chunks within wave
  for (int w = wave + 1; w < 4; ++w) O += wredf[w];

  float slog = 0.0f;
#pragma unroll
  for (int e = 0; e < PPT; ++e) slog += __logf(suf[e] + O);

  for (int off = 32; off; off >>= 1) slog += __shfl_down(slog, off);
  if (lane == 0) wmax[wave] = slog;    // reuse as scratch
  __syncthreads();
  if (tid == 0) {
    float tot2 = wmax[0] + wmax[1] + wmax[2] + wmax[3];
    float rowval = (float)L * sM + tot2 - sSum;
    atomicAdd(out, rowval * invB);
  }
}

extern "C" void kernel_launch(void* const* d_in, const int* in_sizes, int n_in,
                              void* d_out, int out_size, void* d_ws, size_t ws_size,
                              hipStream_t stream) {
  const float* preds = (const float*)d_in[0];
  const float* labels = (const float*)d_in[1];
  float* out = (float*)d_out;
  const int B = in_sizes[0] / L;

  zero_out_kernel<<<1, 1, 0, stream>>>(out);
  listmle_kernel<<<B, NT, 0, stream>>>(preds, labels, out, 1.0f / (float)B);
}